// Round 5
// baseline (2391.194 us; speedup 1.0000x reference)
//
#include <hip/hip_runtime.h>
#include <hip/hip_bf16.h>

// Sizes fixed by the problem
#define BB 128
#define SS 1024
#define FF 512
#define HH 128
#define G3 384   // 3*H

// ---------------------------------------------------------------------------
// lengths: len[b] = #rows t with sum_f x[b,t,f] != 0
// ---------------------------------------------------------------------------
__global__ void zero_len_kernel(int* len) { len[threadIdx.x] = 0; }

__global__ void lengths_kernel(const float* __restrict__ x, int* __restrict__ len) {
    int wave = threadIdx.x >> 6;
    int lane = threadIdx.x & 63;
    long row = (long)blockIdx.x * 4 + wave;   // 0 .. 131071
    const float4* p = (const float4*)&x[row * FF + lane * 8];
    float4 v0 = p[0], v1 = p[1];
    float s = v0.x + v0.y + v0.z + v0.w + v1.x + v1.y + v1.z + v1.w;
    #pragma unroll
    for (int off = 32; off > 0; off >>= 1) s += __shfl_down(s, off, 64);
    if (lane == 0 && s != 0.0f) atomicAdd(&len[row >> 10], 1);
}

// rank[i] = stable rank under descending-length sort (ties -> lower index first)
__global__ void rank_kernel(const int* __restrict__ len, int* __restrict__ rank) {
    int i = threadIdx.x;
    int li = len[i];
    int r = 0;
    for (int jj = 0; jj < BB; jj++) {
        int lj = len[jj];
        if (lj > li || (lj == li && jj < i)) r++;
    }
    rank[i] = r;
}

// ---------------------------------------------------------------------------
// C[M,N] = A[M,K] @ B[N,K]^T + bias[N]   (fp32, 128x128 tile, 8x8/thread)
// ---------------------------------------------------------------------------
__global__ __launch_bounds__(256) void gemm_abt(
    const float* __restrict__ A, const float* __restrict__ B,
    const float* __restrict__ bias, float* __restrict__ C,
    int M, int N, int K)
{
    __shared__ float As[16][132];
    __shared__ float Bs[16][132];
    const int tid = threadIdx.x;
    const int tm0 = blockIdx.x * 128;
    const int tn0 = blockIdx.y * 128;
    const int row = tid >> 2;          // 0..63
    const int c4  = (tid & 3) * 4;     // 0,4,8,12
    const int ty  = tid >> 4;          // 0..15
    const int tx  = tid & 15;          // 0..15

    float acc[8][8];
    #pragma unroll
    for (int i = 0; i < 8; i++)
        #pragma unroll
        for (int j = 0; j < 8; j++) acc[i][j] = 0.0f;

    for (int k0 = 0; k0 < K; k0 += 16) {
        float4 av0 = *(const float4*)&A[(size_t)(tm0 + row)      * K + k0 + c4];
        float4 av1 = *(const float4*)&A[(size_t)(tm0 + row + 64) * K + k0 + c4];
        float4 bv0 = *(const float4*)&B[(size_t)(tn0 + row)      * K + k0 + c4];
        float4 bv1 = *(const float4*)&B[(size_t)(tn0 + row + 64) * K + k0 + c4];
        __syncthreads();
        As[c4 + 0][row] = av0.x; As[c4 + 1][row] = av0.y;
        As[c4 + 2][row] = av0.z; As[c4 + 3][row] = av0.w;
        As[c4 + 0][row + 64] = av1.x; As[c4 + 1][row + 64] = av1.y;
        As[c4 + 2][row + 64] = av1.z; As[c4 + 3][row + 64] = av1.w;
        Bs[c4 + 0][row] = bv0.x; Bs[c4 + 1][row] = bv0.y;
        Bs[c4 + 2][row] = bv0.z; Bs[c4 + 3][row] = bv0.w;
        Bs[c4 + 0][row + 64] = bv1.x; Bs[c4 + 1][row + 64] = bv1.y;
        Bs[c4 + 2][row + 64] = bv1.z; Bs[c4 + 3][row + 64] = bv1.w;
        __syncthreads();
        #pragma unroll
        for (int kk = 0; kk < 16; kk++) {
            float a[8], b[8];
            *(float4*)&a[0] = *(const float4*)&As[kk][ty * 8];
            *(float4*)&a[4] = *(const float4*)&As[kk][ty * 8 + 4];
            *(float4*)&b[0] = *(const float4*)&Bs[kk][tx * 8];
            *(float4*)&b[4] = *(const float4*)&Bs[kk][tx * 8 + 4];
            #pragma unroll
            for (int i = 0; i < 8; i++)
                #pragma unroll
                for (int j = 0; j < 8; j++)
                    acc[i][j] = fmaf(a[i], b[j], acc[i][j]);
        }
    }

    float bv[8];
    #pragma unroll
    for (int j = 0; j < 8; j++) bv[j] = bias[tn0 + tx * 8 + j];
    #pragma unroll
    for (int i = 0; i < 8; i++) {
        size_t crow = (size_t)(tm0 + ty * 8 + i) * N + tn0 + tx * 8;
        float4 o0, o1;
        o0.x = acc[i][0] + bv[0]; o0.y = acc[i][1] + bv[1];
        o0.z = acc[i][2] + bv[2]; o0.w = acc[i][3] + bv[3];
        o1.x = acc[i][4] + bv[4]; o1.y = acc[i][5] + bv[5];
        o1.z = acc[i][6] + bv[6]; o1.w = acc[i][7] + bv[7];
        *(float4*)&C[crow]     = o0;
        *(float4*)&C[crow + 4] = o1;
    }
}

// ---------------------------------------------------------------------------
// GRU recurrence, v5. One block (512 thr = 8 waves) per batch row.
// Thread (j = tid>>2, kq = tid&3): owns Whh[{r,z,n} rows j][kq*32 .. +32)
// = 96 floats in VGPRs.
// v5 fix (round-4 post-mortem): __launch_bounds__'s 2nd arg is only a MIN
// waves/EU; the allocator still TARGETS max occupancy (it squeezed to ~76
// VGPR = 6-waves/SIMD budget, spilling/remat'ing the weights into per-step
// L2 reloads). amdgpu_waves_per_eu(2,2) pins the occupancy target to what we
// actually run (1 block/CU = 2 waves/SIMD), unlocking the 256-VGPR budget so
// the 96 weights stay resident. asm pin kept as belt-and-braces.
// ---------------------------------------------------------------------------
__device__ __forceinline__ float fast_sigmoid(float x) {
    return __builtin_amdgcn_rcpf(1.0f + __expf(-x));
}
__device__ __forceinline__ float fast_tanh(float x) {
    // 1 - 2/(1+exp(2x)); correct limits at +-inf
    return 1.0f - 2.0f * __builtin_amdgcn_rcpf(1.0f + __expf(2.0f * x));
}

template<int FINAL>
__global__ __launch_bounds__(512, 2) __attribute__((amdgpu_waves_per_eu(2, 2)))
void gru_rec(
    const float* __restrict__ xg,    // [B,S,3H]
    const float* __restrict__ Whh,   // [3H,H]
    const float* __restrict__ bhh,   // [3H]
    float* __restrict__ h_out,       // [B,S,H] (FINAL=0) or [B,H] (FINAL=1)
    const int* __restrict__ len,
    const int* __restrict__ rank)
{
    const int b   = blockIdx.x;
    const int tid = threadIdx.x;
    const int j   = tid >> 2;     // 0..127 output lane
    const int kq  = tid & 3;      // K-quarter (32 elems)

    __shared__ __align__(16) float h_lds[2][HH];

    // 3 gates x 32 weights in VGPRs, pre-rotated by 2*kq float4-slots
    float4 wv[3][8];
    #pragma unroll
    for (int g = 0; g < 3; g++) {
        const float4* wr = (const float4*)&Whh[(size_t)(g * HH + j) * HH + kq * 32];
        #pragma unroll
        for (int q = 0; q < 8; q++) wv[g][q] = wr[(q + 2 * kq) & 7];  // runtime idx into GLOBAL mem only
    }
    // Pin: force all 96 weights to live in VGPRs; the empty asm is treated as
    // writing these values, so reloading from Whh is no longer legal.
    #pragma unroll
    for (int g = 0; g < 3; g++)
        #pragma unroll
        for (int q = 0; q < 8; q++)
            asm volatile("" : "+v"(wv[g][q].x), "+v"(wv[g][q].y),
                              "+v"(wv[g][q].z), "+v"(wv[g][q].w));

    float b_r = 0.f, b_z = 0.f, b_n = 0.f;
    if (kq == 0) { b_r = bhh[j]; b_z = bhh[HH + j]; b_n = bhh[2 * HH + j]; }
    const float* xgb = xg + (size_t)b * SS * G3;

    if (tid < 2 * HH) ((float*)h_lds)[tid] = 0.0f;
    float hprev = 0.0f, osum = 0.0f;
    const int L = FINAL ? len[b] : 0;

    // prefetch xg for t=0 (only gate lanes need it)
    float xr = 0.f, xz = 0.f, xn = 0.f;
    if (kq == 0) { xr = xgb[j]; xz = xgb[HH + j]; xn = xgb[2 * HH + j]; }
    __syncthreads();

    for (int t = 0; t < SS; t++) {
        // lagged coalesced global write of h_{t-1} (wave 1)
        if (!FINAL && t > 0 && tid >= 64 && tid < 96) {
            int c = tid - 64;
            float4 hv = ((const float4*)h_lds[t & 1])[c];
            *(float4*)&h_out[((size_t)b * SS + (t - 1)) * HH + c * 4] = hv;
        }
        // prefetch xg for t+1
        float nxr = 0.f, nxz = 0.f, nxn = 0.f;
        if (kq == 0 && t + 1 < SS) {
            const float* p = xgb + (size_t)(t + 1) * G3;
            nxr = p[j]; nxz = p[HH + j]; nxn = p[2 * HH + j];
        }
        // matvec: 3 gates x 32 elems; LDS address carries the stagger, the
        // register arrays are indexed with the static q.
        const float4* h4 = (const float4*)h_lds[t & 1];
        float4 ar = {0,0,0,0}, az = {0,0,0,0}, an = {0,0,0,0};
        #pragma unroll
        for (int q = 0; q < 8; q++) {
            float4 hv = h4[kq * 8 + ((q + 2 * kq) & 7)];   // runtime LDS addr: OK
            float4 w0 = wv[0][q], w1 = wv[1][q], w2 = wv[2][q];  // static reg idx
            ar.x = fmaf(w0.x, hv.x, ar.x); ar.y = fmaf(w0.y, hv.y, ar.y);
            ar.z = fmaf(w0.z, hv.z, ar.z); ar.w = fmaf(w0.w, hv.w, ar.w);
            az.x = fmaf(w1.x, hv.x, az.x); az.y = fmaf(w1.y, hv.y, az.y);
            az.z = fmaf(w1.z, hv.z, az.z); az.w = fmaf(w1.w, hv.w, az.w);
            an.x = fmaf(w2.x, hv.x, an.x); an.y = fmaf(w2.y, hv.y, an.y);
            an.z = fmaf(w2.z, hv.z, an.z); an.w = fmaf(w2.w, hv.w, an.w);
        }
        float a0 = (ar.x + ar.y) + (ar.z + ar.w);
        float a1 = (az.x + az.y) + (az.z + az.w);
        float a2 = (an.x + an.y) + (an.z + an.w);
        a0 += __shfl_xor(a0, 1, 64); a1 += __shfl_xor(a1, 1, 64); a2 += __shfl_xor(a2, 1, 64);
        a0 += __shfl_xor(a0, 2, 64); a1 += __shfl_xor(a1, 2, 64); a2 += __shfl_xor(a2, 2, 64);
        if (kq == 0) {
            float r = fast_sigmoid(xr + a0 + b_r);
            float z = fast_sigmoid(xz + a1 + b_z);
            float n = fast_tanh(xn + r * (a2 + b_n));
            float h = (1.0f - z) * n + z * hprev;
            hprev = h;
            h_lds[(t + 1) & 1][j] = h;
            if (FINAL) { if (t < L) osum += h; }
        }
        xr = nxr; xz = nxz; xn = nxn;
        __syncthreads();
    }
    if (!FINAL && tid >= 64 && tid < 96) {
        int c = tid - 64;
        float4 hv = ((const float4*)h_lds[SS & 1])[c];
        *(float4*)&h_out[((size_t)b * SS + (SS - 1)) * HH + c * 4] = hv;
    }
    if (FINAL && kq == 0) {
        h_out[(size_t)rank[b] * HH + j] = osum * (1.0f / (float)SS);
    }
}

// ---------------------------------------------------------------------------
extern "C" void kernel_launch(void* const* d_in, const int* in_sizes, int n_in,
                              void* d_out, int out_size, void* d_ws, size_t ws_size,
                              hipStream_t stream) {
    const float* x    = (const float*)d_in[0];
    const float* Wp   = (const float*)d_in[1];
    const float* bp   = (const float*)d_in[2];
    const float* Wih0 = (const float*)d_in[3];
    const float* Whh0 = (const float*)d_in[4];
    const float* bih0 = (const float*)d_in[5];
    const float* bhh0 = (const float*)d_in[6];
    const float* Wih1 = (const float*)d_in[7];
    const float* Whh1 = (const float*)d_in[8];
    const float* bih1 = (const float*)d_in[9];
    const float* bhh1 = (const float*)d_in[10];
    float* out = (float*)d_out;

    // workspace layout: [len 128 int][rank 128 int] ... 4KB ... proj/h1 (64MB), xg (192MB)
    int* len  = (int*)d_ws;
    int* rank = len + 128;
    float* proj = (float*)((char*)d_ws + 4096);                  // [B*S, H]  also reused as h1
    float* xgb  = proj + (size_t)BB * SS * HH;                   // [B*S, 3H]

    // 1) lengths + rank
    zero_len_kernel<<<1, 128, 0, stream>>>(len);
    lengths_kernel<<<(BB * SS) / 4, 256, 0, stream>>>(x, len);
    rank_kernel<<<1, 128, 0, stream>>>(len, rank);

    // 2) proj = x @ Wp^T + bp       [131072,512] x [128,512]^T
    gemm_abt<<<dim3(BB * SS / 128, HH / 128), 256, 0, stream>>>(x, Wp, bp, proj,
                                                               BB * SS, HH, FF);
    // 3) xg0 = proj @ Wih0^T + bih0 [131072,128] x [384,128]^T
    gemm_abt<<<dim3(BB * SS / 128, G3 / 128), 256, 0, stream>>>(proj, Wih0, bih0, xgb,
                                                                BB * SS, G3, HH);
    // 4) layer-1 recurrence -> h1 (into proj region; proj is dead now)
    gru_rec<0><<<BB, 512, 0, stream>>>(xgb, Whh0, bhh0, proj, len, rank);

    // 5) xg1 = h1 @ Wih1^T + bih1 (overwrite xg region)
    gemm_abt<<<dim3(BB * SS / 128, G3 / 128), 256, 0, stream>>>(proj, Wih1, bih1, xgb,
                                                                BB * SS, G3, HH);
    // 6) layer-2 recurrence + masked mean -> out at sorted rank
    gru_rec<1><<<BB, 512, 0, stream>>>(xgb, Whh1, bhh1, out, len, rank);
}

// Round 6
// 1978.726 us; speedup vs baseline: 1.2085x; 1.2085x over previous
//
#include <hip/hip_runtime.h>
#include <hip/hip_bf16.h>

// Sizes fixed by the problem
#define BB 128
#define SS 1024
#define FF 512
#define HH 128
#define G3 384   // 3*H

typedef __attribute__((ext_vector_type(8))) short bf16x8;
typedef __attribute__((ext_vector_type(4))) float f32x4;

// ---------------------------------------------------------------------------
// lengths: len[b] = #rows t with sum_f x[b,t,f] != 0
// ---------------------------------------------------------------------------
__global__ void zero_len_kernel(int* len) { len[threadIdx.x] = 0; }

__global__ void lengths_kernel(const float* __restrict__ x, int* __restrict__ len) {
    int wave = threadIdx.x >> 6;
    int lane = threadIdx.x & 63;
    long row = (long)blockIdx.x * 4 + wave;   // 0 .. 131071
    const float4* p = (const float4*)&x[row * FF + lane * 8];
    float4 v0 = p[0], v1 = p[1];
    float s = v0.x + v0.y + v0.z + v0.w + v1.x + v1.y + v1.z + v1.w;
    #pragma unroll
    for (int off = 32; off > 0; off >>= 1) s += __shfl_down(s, off, 64);
    if (lane == 0 && s != 0.0f) atomicAdd(&len[row >> 10], 1);
}

// rank[i] = stable rank under descending-length sort (ties -> lower index first)
__global__ void rank_kernel(const int* __restrict__ len, int* __restrict__ rank) {
    int i = threadIdx.x;
    int li = len[i];
    int r = 0;
    for (int jj = 0; jj < BB; jj++) {
        int lj = len[jj];
        if (lj > li || (lj == li && jj < i)) r++;
    }
    rank[i] = r;
}

// ---------------------------------------------------------------------------
// bf16 split helpers (RTN-even rounding; no NaN/inf in this data)
// ---------------------------------------------------------------------------
__device__ __forceinline__ short bf_hi(float w, float& hf) {
    unsigned u = __builtin_bit_cast(unsigned, w);
    unsigned r = (u + 0x7FFFu + ((u >> 16) & 1u)) & 0xFFFF0000u;
    hf = __builtin_bit_cast(float, r);
    return (short)(r >> 16);
}
__device__ __forceinline__ short bf_rn(float w) {
    unsigned u = __builtin_bit_cast(unsigned, w);
    unsigned r = u + 0x7FFFu + ((u >> 16) & 1u);
    return (short)(r >> 16);
}

// ---------------------------------------------------------------------------
// Split-bf16 MFMA GEMM: C[M,N] = A[M,K] @ W[N,K]^T + bias[N]
// A,W fp32 in; per-element split a = hi(a)+lo(a) (bf16 each); 3 MFMA passes
// (hh + hl + lh) -> fp32-grade accuracy at MFMA rate.
// Block: 256 thr = 4 waves. M-tile 64 (16 rows/wave), N-tile 128 (8 subtiles).
// W k-slice (128 cols x 32 k) converted + staged into LDS each k-step.
// mfma_f32_16x16x32_bf16 layouts (verified, guide s3/m89):
//   A: row = lane&15, k = 8*(lane>>4)+e ; B: col = lane&15, same k
//   D: col = lane&15, row = 4*(lane>>4)+reg
// ---------------------------------------------------------------------------
__global__ __launch_bounds__(256) void gemm_mfma(
    const float* __restrict__ A, const float* __restrict__ W,
    const float* __restrict__ bias, float* __restrict__ C,
    int M, int N, int K)
{
    const int tid  = threadIdx.x;
    const int wvid = tid >> 6;
    const int lane = tid & 63;
    const int m0   = blockIdx.x * 64 + wvid * 16;
    const int n0   = blockIdx.y * 128;
    const int KS   = K >> 5;

    __shared__ __align__(16) short sh[2][8][64][8];   // [plane][ntile][lane][e] 16KB

    f32x4 acc[8];
    #pragma unroll
    for (int i = 0; i < 8; i++) acc[i] = (f32x4){0.f, 0.f, 0.f, 0.f};

    const int arow = m0 + (lane & 15);
    const int koff = (lane >> 4) << 3;

    for (int ks = 0; ks < KS; ks++) {
        __syncthreads();   // previous iteration's sh reads complete
        // stage + convert W k-slice: 512 (ntile,ln) fragments, 2 per thread
        #pragma unroll
        for (int i = 0; i < 2; i++) {
            int p  = tid + i * 256;
            int nt = p >> 6, ln = p & 63;
            const float* src = &W[(size_t)(n0 + nt * 16 + (ln & 15)) * K
                                  + ks * 32 + ((ln >> 4) << 3)];
            float w8[8];
            *(float4*)&w8[0] = *(const float4*)&src[0];
            *(float4*)&w8[4] = *(const float4*)&src[4];
            short hi8[8], lo8[8];
            #pragma unroll
            for (int e = 0; e < 8; e++) {
                float hf; hi8[e] = bf_hi(w8[e], hf);
                lo8[e] = bf_rn(w8[e] - hf);
            }
            *(bf16x8*)&sh[0][nt][ln][0] = *(bf16x8*)hi8;
            *(bf16x8*)&sh[1][nt][ln][0] = *(bf16x8*)lo8;
        }
        // A fragment: 8 consecutive fp32 along K, split to hi/lo bf16
        const float* ap = &A[(size_t)arow * K + ks * 32 + koff];
        float av[8];
        *(float4*)&av[0] = *(const float4*)&ap[0];
        *(float4*)&av[4] = *(const float4*)&ap[4];
        short ah[8], al[8];
        #pragma unroll
        for (int e = 0; e < 8; e++) {
            float hf; ah[e] = bf_hi(av[e], hf);
            al[e] = bf_rn(av[e] - hf);
        }
        bf16x8 ahi = *(bf16x8*)ah, alo = *(bf16x8*)al;
        __syncthreads();   // sh ready
        #pragma unroll
        for (int nt = 0; nt < 8; nt++) {
            bf16x8 bhi = *(bf16x8*)&sh[0][nt][lane][0];
            bf16x8 blo = *(bf16x8*)&sh[1][nt][lane][0];
            acc[nt] = __builtin_amdgcn_mfma_f32_16x16x32_bf16(ahi, bhi, acc[nt], 0, 0, 0);
            acc[nt] = __builtin_amdgcn_mfma_f32_16x16x32_bf16(ahi, blo, acc[nt], 0, 0, 0);
            acc[nt] = __builtin_amdgcn_mfma_f32_16x16x32_bf16(alo, bhi, acc[nt], 0, 0, 0);
        }
    }
    const int crow = m0 + ((lane >> 4) << 2);
    const int ccol = n0 + (lane & 15);
    #pragma unroll
    for (int nt = 0; nt < 8; nt++) {
        int col = ccol + nt * 16;
        float bv = bias[col];
        #pragma unroll
        for (int r = 0; r < 4; r++)
            C[(size_t)(crow + r) * N + col] = acc[nt][r] + bv;
    }
}

// ---------------------------------------------------------------------------
// GRU recurrence, v6. One block (512 thr = 8 waves) per batch row.
// Thread (j = tid>>2, kq = tid&3): owns Whh[{r,z,n} rows j][kq*32 .. +32)
// = 96 floats that MUST be VGPR-resident (round-5 analysis: reloading them
// is 192 KB/step/CU from L2 = 1715 cy/step = the whole kernel time).
// v6 fix: __launch_bounds__ removed entirely — it emits its own
// amdgpu-waves-per-eu that overrode the attribute in rounds 4/5. Only
// amdgpu_flat_work_group_size(512,512) + amdgpu_waves_per_eu(2,2) now, so
// the allocator targets exactly 2 waves/SIMD -> 256-VGPR budget.
// ---------------------------------------------------------------------------
__device__ __forceinline__ float fast_sigmoid(float x) {
    return __builtin_amdgcn_rcpf(1.0f + __expf(-x));
}
__device__ __forceinline__ float fast_tanh(float x) {
    return 1.0f - 2.0f * __builtin_amdgcn_rcpf(1.0f + __expf(2.0f * x));
}

template<int FINAL>
__global__ __attribute__((amdgpu_flat_work_group_size(512, 512), amdgpu_waves_per_eu(2, 2)))
void gru_rec(
    const float* __restrict__ xg,    // [B,S,3H]
    const float* __restrict__ Whh,   // [3H,H]
    const float* __restrict__ bhh,   // [3H]
    float* __restrict__ h_out,       // [B,S,H] (FINAL=0) or [B,H] (FINAL=1)
    const int* __restrict__ len,
    const int* __restrict__ rank)
{
    const int b   = blockIdx.x;
    const int tid = threadIdx.x;
    const int j   = tid >> 2;     // 0..127 output lane
    const int kq  = tid & 3;      // K-quarter (32 elems)

    __shared__ __align__(16) float h_lds[2][HH];

    // 3 gates x 32 weights in VGPRs, pre-rotated by 2*kq float4-slots
    float4 wv[3][8];
    #pragma unroll
    for (int g = 0; g < 3; g++) {
        const float4* wr = (const float4*)&Whh[(size_t)(g * HH + j) * HH + kq * 32];
        #pragma unroll
        for (int q = 0; q < 8; q++) wv[g][q] = wr[(q + 2 * kq) & 7];  // runtime idx into GLOBAL mem only
    }
    // Pin: the empty asm "writes" the values, so re-loading from Whh is illegal.
    #pragma unroll
    for (int g = 0; g < 3; g++)
        #pragma unroll
        for (int q = 0; q < 8; q++)
            asm volatile("" : "+v"(wv[g][q].x), "+v"(wv[g][q].y),
                              "+v"(wv[g][q].z), "+v"(wv[g][q].w));

    float b_r = 0.f, b_z = 0.f, b_n = 0.f;
    if (kq == 0) { b_r = bhh[j]; b_z = bhh[HH + j]; b_n = bhh[2 * HH + j]; }
    const float* xgb = xg + (size_t)b * SS * G3;

    if (tid < 2 * HH) ((float*)h_lds)[tid] = 0.0f;
    float hprev = 0.0f, osum = 0.0f;
    const int L = FINAL ? len[b] : 0;

    float xr = 0.f, xz = 0.f, xn = 0.f;
    if (kq == 0) { xr = xgb[j]; xz = xgb[HH + j]; xn = xgb[2 * HH + j]; }
    __syncthreads();

    for (int t = 0; t < SS; t++) {
        if (!FINAL && t > 0 && tid >= 64 && tid < 96) {
            int c = tid - 64;
            float4 hv = ((const float4*)h_lds[t & 1])[c];
            *(float4*)&h_out[((size_t)b * SS + (t - 1)) * HH + c * 4] = hv;
        }
        float nxr = 0.f, nxz = 0.f, nxn = 0.f;
        if (kq == 0 && t + 1 < SS) {
            const float* p = xgb + (size_t)(t + 1) * G3;
            nxr = p[j]; nxz = p[HH + j]; nxn = p[2 * HH + j];
        }
        const float4* h4 = (const float4*)h_lds[t & 1];
        float4 ar = {0,0,0,0}, az = {0,0,0,0}, an = {0,0,0,0};
        #pragma unroll
        for (int q = 0; q < 8; q++) {
            float4 hv = h4[kq * 8 + ((q + 2 * kq) & 7)];   // runtime LDS addr: OK
            float4 w0 = wv[0][q], w1 = wv[1][q], w2 = wv[2][q];  // static reg idx
            ar.x = fmaf(w0.x, hv.x, ar.x); ar.y = fmaf(w0.y, hv.y, ar.y);
            ar.z = fmaf(w0.z, hv.z, ar.z); ar.w = fmaf(w0.w, hv.w, ar.w);
            az.x = fmaf(w1.x, hv.x, az.x); az.y = fmaf(w1.y, hv.y, az.y);
            az.z = fmaf(w1.z, hv.z, az.z); az.w = fmaf(w1.w, hv.w, az.w);
            an.x = fmaf(w2.x, hv.x, an.x); an.y = fmaf(w2.y, hv.y, an.y);
            an.z = fmaf(w2.z, hv.z, an.z); an.w = fmaf(w2.w, hv.w, an.w);
        }
        float a0 = (ar.x + ar.y) + (ar.z + ar.w);
        float a1 = (az.x + az.y) + (az.z + az.w);
        float a2 = (an.x + an.y) + (an.z + an.w);
        a0 += __shfl_xor(a0, 1, 64); a1 += __shfl_xor(a1, 1, 64); a2 += __shfl_xor(a2, 1, 64);
        a0 += __shfl_xor(a0, 2, 64); a1 += __shfl_xor(a1, 2, 64); a2 += __shfl_xor(a2, 2, 64);
        if (kq == 0) {
            float r = fast_sigmoid(xr + a0 + b_r);
            float z = fast_sigmoid(xz + a1 + b_z);
            float n = fast_tanh(xn + r * (a2 + b_n));
            float h = (1.0f - z) * n + z * hprev;
            hprev = h;
            h_lds[(t + 1) & 1][j] = h;
            if (FINAL) { if (t < L) osum += h; }
        }
        xr = nxr; xz = nxz; xn = nxn;
        __syncthreads();
    }
    if (!FINAL && tid >= 64 && tid < 96) {
        int c = tid - 64;
        float4 hv = ((const float4*)h_lds[SS & 1])[c];
        *(float4*)&h_out[((size_t)b * SS + (SS - 1)) * HH + c * 4] = hv;
    }
    if (FINAL && kq == 0) {
        h_out[(size_t)rank[b] * HH + j] = osum * (1.0f / (float)SS);
    }
}

// ---------------------------------------------------------------------------
extern "C" void kernel_launch(void* const* d_in, const int* in_sizes, int n_in,
                              void* d_out, int out_size, void* d_ws, size_t ws_size,
                              hipStream_t stream) {
    const float* x    = (const float*)d_in[0];
    const float* Wp   = (const float*)d_in[1];
    const float* bp   = (const float*)d_in[2];
    const float* Wih0 = (const float*)d_in[3];
    const float* Whh0 = (const float*)d_in[4];
    const float* bih0 = (const float*)d_in[5];
    const float* bhh0 = (const float*)d_in[6];
    const float* Wih1 = (const float*)d_in[7];
    const float* Whh1 = (const float*)d_in[8];
    const float* bih1 = (const float*)d_in[9];
    const float* bhh1 = (const float*)d_in[10];
    float* out = (float*)d_out;

    // workspace: [len 128 int][rank 128 int] ... 4KB ... proj/h1 (64MB), xg (192MB)
    int* len  = (int*)d_ws;
    int* rank = len + 128;
    float* proj = (float*)((char*)d_ws + 4096);                  // [B*S, H]  reused as h1
    float* xgb  = proj + (size_t)BB * SS * HH;                   // [B*S, 3H]

    // 1) lengths + rank
    zero_len_kernel<<<1, 128, 0, stream>>>(len);
    lengths_kernel<<<(BB * SS) / 4, 256, 0, stream>>>(x, len);
    rank_kernel<<<1, 128, 0, stream>>>(len, rank);

    // 2) proj = x @ Wp^T + bp       [131072,512] x [128,512]^T
    gemm_mfma<<<dim3(BB * SS / 64, 1), 256, 0, stream>>>(x, Wp, bp, proj,
                                                         BB * SS, HH, FF);
    // 3) xg0 = proj @ Wih0^T + bih0 [131072,128] x [384,128]^T
    gemm_mfma<<<dim3(BB * SS / 64, 3), 256, 0, stream>>>(proj, Wih0, bih0, xgb,
                                                         BB * SS, G3, HH);
    // 4) layer-1 recurrence -> h1 (into proj region; proj is dead now)
    gru_rec<0><<<BB, 512, 0, stream>>>(xgb, Whh0, bhh0, proj, len, rank);

    // 5) xg1 = h1 @ Wih1^T + bih1 (overwrite xg region)
    gemm_mfma<<<dim3(BB * SS / 64, 3), 256, 0, stream>>>(proj, Wih1, bih1, xgb,
                                                         BB * SS, G3, HH);
    // 6) layer-2 recurrence + masked mean -> out at sorted rank
    gru_rec<1><<<BB, 512, 0, stream>>>(xgb, Whh1, bhh1, out, len, rank);
}